// Round 16
// baseline (2459.269 us; speedup 1.0000x reference)
//
#include <hip/hip_runtime.h>
#include <hip/hip_bf16.h>

// PeepholeLSTM: SEQ=512, BATCH=64, IN=512, HS=1024, FORGET_BIAS=0
// out = [hidden_seq (512*64*1024) | c_T (64*1024) | h_T (64*1024)] f32
//
// Round-16 = round-15 + PER-GROUP gates (skew absorption).
//   r15 showed latency/skew-bound, not BW-bound (plain vs sc0sc1 consume = flat).
//   The single gate = max over 128 producers every step (convoy). Consume group G
//   reads exactly gsrc [32G,32G+32) -> gate each group on its own 32 tags, pipelined:
//   GATE(0) ISSUE(0) GATE(1) ISSUE(1) MFMA(0) GATE(2) ISSUE(2) MFMA(1) GATE(3)
//   ISSUE(3) MFMA(2) wait MFMA(3). Each gate's vmcnt(0) drains prior payload loads
//   (latency hidden under poll); consumption starts at max-over-32 not max-over-128;
//   gates 1-3 pass first-poll in steady state. r13's per-group attempt failed only
//   because its payload was poisoned-plain; payload here = r14/r15 single-shot
//   (unique-per-step slots, seqlock: producer drains exchanges to LLC before tag).

#define SEQN 512
#define BATCH 64
#define INDIM 512
#define HSZ 1024
#define NWG 128

typedef __attribute__((ext_vector_type(8))) short s16x8;
typedef __attribute__((ext_vector_type(4))) float f32x4;
typedef __attribute__((ext_vector_type(2))) float f32x2;
typedef __attribute__((ext_vector_type(4))) int i32x4;
typedef unsigned long long u64;

__device__ __forceinline__ short f2bf(float f) {
  __hip_bfloat16 b = __float2bfloat16(f);
  short s;
  __builtin_memcpy(&s, &b, 2);
  return s;
}
__device__ __forceinline__ float sigf(float x) { return 1.f / (1.f + __expf(-x)); }
__device__ __forceinline__ float tanh_fast(float x) { return 2.f / (1.f + __expf(-2.f * x)) - 1.f; }

// ---------------------------------------------------------------------------
// prep_w: col = gate*1024 + hidx; hidx = g*8+off; pc = off*4+gate.
__global__ __launch_bounds__(256) void prep_w(const float* __restrict__ W,
                                              short* __restrict__ WxP,
                                              short* __restrict__ WhP) {
  int idx = blockIdx.x * 256 + threadIdx.x;
  if (idx >= 1536 * 4096) return;
  int k = idx >> 12, col = idx & 4095;
  short b = f2bf(W[idx]);
  int gate = col >> 10, hidx = col & 1023;
  int g = hidx >> 3, off = hidx & 7;
  int pc = off * 4 + gate;
  if (k < 512) {
    WxP[(size_t)(((g * 64 + (k >> 3)) * 32 + pc) << 3) + (k & 7)] = b;
  } else {
    int kh = k - 512;
    WhP[(size_t)(((g * 128 + (kh >> 3)) * 32 + pc) << 3) + (kh & 7)] = b;
  }
}

// ---------------------------------------------------------------------------
// prep_x: x[t][m][k] f32 -> xbp[t][kb][m][8] bf16.
__global__ __launch_bounds__(256) void prep_x(const float* __restrict__ x,
                                              short* __restrict__ xbp) {
  int idx = blockIdx.x * 256 + threadIdx.x;
  if (idx >= SEQN * 64 * 64) return;
  int kb = idx & 63, m = (idx >> 6) & 63, t = idx >> 12;
  const float4* xp = reinterpret_cast<const float4*>(x + ((size_t)t * 64 + m) * 512 + kb * 8);
  float4 a = xp[0], c = xp[1];
  s16x8 v;
  v[0] = f2bf(a.x); v[1] = f2bf(a.y); v[2] = f2bf(a.z); v[3] = f2bf(a.w);
  v[4] = f2bf(c.x); v[5] = f2bf(c.y); v[6] = f2bf(c.z); v[7] = f2bf(c.w);
  reinterpret_cast<s16x8*>(xbp)[((size_t)t * 64 + kb) * 64 + m] = v;
}

// ---------------------------------------------------------------------------
// lstm_seq: 128 WGs x 256. WG g: hidden [8g,8g+8). Wave w: batch rows [16w,16w+16).
// Lane l: m = w*16+(l&15), q4 = l>>4, hidden cols c0 = 8g+q4, c1 = c0+4, all 4 gates.
// hq[t][gsrc 128][m 64][j 2] u64 = 4 bf16 (k-order; dwordx4 [j0|j1] IS the B-frag).
// tagv[t][w 4][gsrc 128] u64 == t  <=>  producer (gsrc, wave w) h_{t-1} acked at LLC.
// Slots are NOT reused: plain consume loads are first-touch => L2 fills always fresh.
__global__ __launch_bounds__(256, 1) void lstm_seq(const short* __restrict__ xbp,
                                                   const short* __restrict__ WhP,
                                                   const short* __restrict__ WxP,
                                                   const float* __restrict__ bias,
                                                   const float* __restrict__ peep_i,
                                                   const float* __restrict__ peep_f,
                                                   const float* __restrict__ peep_o,
                                                   u64* hq,
                                                   u64* tagv,
                                                   float* __restrict__ out) {
  __shared__ short WhS[32768];   // 64KB [kb 128][pc 32][8]
  __shared__ short WxS[16384];   // 32KB [kb  64][pc 32][8]
  __shared__ float outS[512];    //  2KB
  int g = blockIdx.x;
  int tid = threadIdx.x, w = tid >> 6, l = tid & 63;
  {
    const s16x8* src = reinterpret_cast<const s16x8*>(WhP + (size_t)g * 32768);
    s16x8* dst = reinterpret_cast<s16x8*>(WhS);
#pragma unroll
    for (int i = 0; i < 16; ++i) dst[i * 256 + tid] = src[i * 256 + tid];
    const s16x8* src2 = reinterpret_cast<const s16x8*>(WxP + (size_t)g * 16384);
    s16x8* dst2 = reinterpret_cast<s16x8*>(WxS);
#pragma unroll
    for (int i = 0; i < 8; ++i) dst2[i * 256 + tid] = src2[i * 256 + tid];
  }
  int m = w * 16 + (l & 15), q4 = l >> 4, l15 = l & 15;
  int c0 = g * 8 + q4, c1 = c0 + 4;
  float bi0 = bias[c0], bj0 = bias[1024 + c0], bf0 = bias[2048 + c0], bo0 = bias[3072 + c0];
  float bi1 = bias[c1], bj1 = bias[1024 + c1], bf1 = bias[2048 + c1], bo1 = bias[3072 + c1];
  float pi0 = peep_i[c0], pf0 = peep_f[c0], po0 = peep_o[c0];
  float pi1 = peep_i[c1], pf1 = peep_f[c1], po1 = peep_o[c1];
  float cr0 = 0.f, cr1 = 0.f;
  s16x8* WhS16 = reinterpret_cast<s16x8*>(WhS);
  s16x8* WxS16 = reinterpret_cast<s16x8*>(WxS);
  __syncthreads();

// per-group gate: group G consumes gsrc [32G,32G+32). Lane polls tag 32G+(l&31)
// (sc0sc1 = fresh at LLC). First 2 polls spin (no sleep) to cut quantization.
// Side effect: internal vmcnt(0) drains previously-issued payload loads -> MFMAs
// placed after a gate need no separate VWAIT.
#define GATEG(G)                                                                         \
  {                                                                                      \
    const u64* gp_ = tagv + (size_t)t * 512 + (size_t)w * 128 + (G) * 32 + (l & 31);     \
    int guard = 0;                                                                       \
    while (true) {                                                                       \
      u64 gv_;                                                                           \
      asm volatile("global_load_dwordx2 %0, %1, off sc0 sc1" : "=v"(gv_) : "v"(gp_));    \
      asm volatile("s_waitcnt vmcnt(0)" ::: "memory");                                   \
      __builtin_amdgcn_sched_barrier(0);                                                 \
      if (__all((int)(gv_ == (u64)(unsigned)t))) break;                                  \
      if (++guard > (1 << 13)) break; /* fail loud (wrong data), never hang */           \
      if (guard > 2) __builtin_amdgcn_s_sleep(1);                                        \
    }                                                                                    \
  }
// issue group G: 8 x dwordx4/lane, PLAIN cached loads (gate + first-touch => fresh;
// L2 fill shared/merged within the XCD). inline asm keeps vmcnt counts exact.
#define ISSUE(BANK, G)                                                                   \
  {                                                                                      \
    _Pragma("unroll") for (int i = 0; i < 8; ++i) {                                      \
      const u64* p_ = rdq + (size_t)((((G) * 8 + i) * 4 + q4) * 128 + m * 2);            \
      asm volatile("global_load_dwordx4 %0, %1, off" : "=v"(BANK[i]) : "v"(p_));         \
    }                                                                                    \
  }
#define MFMAG(BANK, G)                                                                   \
  {                                                                                      \
    _Pragma("unroll") for (int i = 0; i < 8; ++i) {                                      \
      int kb_ = ((G) * 8 + i) * 4 + q4;                                                  \
      s16x8 bv;                                                                          \
      __builtin_memcpy(&bv, &BANK[i], 16);                                               \
      s16x8 a0 = WhS16[kb_ * 32 + l15];                                                  \
      s16x8 a1 = WhS16[kb_ * 32 + 16 + l15];                                             \
      acc0 = __builtin_amdgcn_mfma_f32_16x16x32_bf16(a0, bv, acc0, 0, 0, 0);             \
      acc1 = __builtin_amdgcn_mfma_f32_16x16x32_bf16(a1, bv, acc1, 0, 0, 0);             \
    }                                                                                    \
  }
#define VWAIT(N)                                                                         \
  asm volatile("s_waitcnt vmcnt(" #N ")" ::: "memory");                                  \
  __builtin_amdgcn_sched_barrier(0);

  for (int t = 0; t < SEQN; ++t) {
    f32x4 acc0 = {0.f, 0.f, 0.f, 0.f}, acc1 = {0.f, 0.f, 0.f, 0.f};
    // ---- x-projection (h-independent; overlaps other WGs' publish) ----
    {
      const s16x8* xt = reinterpret_cast<const s16x8*>(xbp) + (size_t)t * 4096;
#pragma unroll 4
      for (int kk = 0; kk < 16; ++kk) {
        int kb = kk * 4 + q4;
        s16x8 bx = xt[kb * 64 + m];
        s16x8 a0 = WxS16[kb * 32 + l15];
        s16x8 a1 = WxS16[kb * 32 + 16 + l15];
        acc0 = __builtin_amdgcn_mfma_f32_16x16x32_bf16(a0, bx, acc0, 0, 0, 0);
        acc1 = __builtin_amdgcn_mfma_f32_16x16x32_bf16(a1, bx, acc1, 0, 0, 0);
      }
    }
    if (t > 0) {
      // ---- consume: per-group gate -> single-shot loads; gate drains hide latency ----
      const u64* rdq = hq + (size_t)t * 16384;
      i32x4 hA[8], hB[8];
      GATEG(0);
      ISSUE(hA, 0);
      GATEG(1);        // drains -> hA complete
      ISSUE(hB, 1);
      MFMAG(hA, 0);
      GATEG(2);        // drains -> hB complete
      ISSUE(hA, 2);
      MFMAG(hB, 1);
      GATEG(3);        // drains -> hA(2) complete
      ISSUE(hB, 3);
      MFMAG(hA, 2);
      VWAIT(0);
      MFMAG(hB, 3);
    }
    // ---- elementwise (lane-local: all 4 gates of c0 and c1) ----
    float i0 = sigf(acc0[0] + bi0 + cr0 * pi0);
    float f0 = sigf(acc0[2] + bf0 + cr0 * pf0);
    float cn0 = f0 * cr0 + i0 * tanh_fast(acc0[1] + bj0);
    float o0 = sigf(acc0[3] + bo0 + cn0 * po0);
    float h0 = o0 * tanh_fast(cn0);
    cr0 = cn0;
    float i1 = sigf(acc1[0] + bi1 + cr1 * pi1);
    float f1 = sigf(acc1[2] + bf1 + cr1 * pf1);
    float cn1 = f1 * cr1 + i1 * tanh_fast(acc1[1] + bj1);
    float o1 = sigf(acc1[3] + bo1 + cn1 * po1);
    float h1 = o1 * tanh_fast(cn1);
    cr1 = cn1;
    // ---- publish (skip at last step): shfl-pack -> exchanges -> drain -> tag ----
    if (t < SEQN - 1) {
      unsigned myh = (unsigned)(unsigned short)f2bf(h0) |
                     ((unsigned)(unsigned short)f2bf(h1) << 16);
      int base = l15;
      unsigned va = (unsigned)__shfl((int)myh, base);
      unsigned vb = (unsigned)__shfl((int)myh, base + 16);
      unsigned vc = (unsigned)__shfl((int)myh, base + 32);
      unsigned vd = (unsigned)__shfl((int)myh, base + 48);
      if (q4 < 2) {
        u64 q;
        if (q4 == 0)  // j=0: h0 of lanes q4=0..3 = cols 8g+0..3 (k-order)
          q = (u64)(va & 0xFFFFu) | ((u64)(vb & 0xFFFFu) << 16) |
              ((u64)(vc & 0xFFFFu) << 32) | ((u64)(vd & 0xFFFFu) << 48);
        else          // j=1: h1 of lanes q4=0..3 = cols 8g+4..7
          q = (u64)(va >> 16) | ((u64)(vb >> 16) << 16) |
              ((u64)(vc >> 16) << 32) | ((u64)(vd >> 16) << 48);
        (void)__hip_atomic_exchange(hq + (size_t)(t + 1) * 16384 + g * 128 + m * 2 + q4,
                                    q, __ATOMIC_RELAXED, __HIP_MEMORY_SCOPE_AGENT);
      }
      asm volatile("s_waitcnt vmcnt(0)" ::: "memory");  // payload acked at LLC
      if (l == 0)
        (void)__hip_atomic_exchange(tagv + (size_t)(t + 1) * 512 + (size_t)w * 128 + g,
                                    (u64)(unsigned)(t + 1), __ATOMIC_RELAXED,
                                    __HIP_MEMORY_SCOPE_AGENT);
    }
    // ---- coalesced hidden_seq store via wave-local LDS stage (off critical path) ----
    outS[w * 128 + l15 * 8 + q4] = h0;
    outS[w * 128 + l15 * 8 + q4 + 4] = h1;
    {
      f32x2 v = *reinterpret_cast<f32x2*>(&outS[w * 128 + (l >> 2) * 8 + (l & 3) * 2]);
      int row = w * 16 + (l >> 2), col = g * 8 + (l & 3) * 2;
      __builtin_nontemporal_store(
          v, reinterpret_cast<f32x2*>(out + (size_t)t * 65536 + (size_t)row * 1024 + col));
    }
    if (t == SEQN - 1) {
      out[33554432ull + (size_t)m * 1024 + c0] = cn0;  // c_T
      out[33554432ull + (size_t)m * 1024 + c1] = cn1;
      out[33619968ull + (size_t)m * 1024 + c0] = h0;   // h_T
      out[33619968ull + (size_t)m * 1024 + c1] = h1;
    }
  }
#undef GATEG
#undef ISSUE
#undef MFMAG
#undef VWAIT
}

// ---------------------------------------------------------------------------
extern "C" void kernel_launch(void* const* d_in, const int* in_sizes, int n_in,
                              void* d_out, int out_size, void* d_ws, size_t ws_size,
                              hipStream_t stream) {
  const float* x      = (const float*)d_in[0];
  const float* W      = (const float*)d_in[1];
  const float* bias   = (const float*)d_in[2];
  const float* peep_i = (const float*)d_in[3];
  const float* peep_f = (const float*)d_in[4];
  const float* peep_o = (const float*)d_in[5];
  char* ws = (char*)d_ws;
  short* WxP = (short*)(ws);                   //  4194304 B
  short* WhP = (short*)(ws + 4194304ull);      //  8388608 B
  short* xbp = (short*)(ws + 12582912ull);     // 33554432 B
  u64* hq    = (u64*)(ws + 46137344ull);       // 67108864 B (512 x 128KB, NO reuse)
  u64* tagv  = (u64*)(ws + 113246208ull);      //  2097152 B (512 x 4KB per-wave tags)
  // zero tags every launch: gates must only pass on THIS launch's publishes (slots are
  // unique within a launch; memset kills cross-replay tag aliasing). hq needs no
  // memset: gate-pass implies this-launch write at the LLC; consumer L2 lines are
  // first-touch (dispatch acquire invalidated anything older).
  (void)hipMemsetAsync(tagv, 0, 2097152ull, stream);
  prep_w<<<24576, 256, 0, stream>>>(W, WxP, WhP);
  prep_x<<<8192, 256, 0, stream>>>(x, xbp);
  lstm_seq<<<NWG, 256, 0, stream>>>(xbp, WhP, WxP, bias, peep_i, peep_f, peep_o, hq,
                                    tagv, (float*)d_out);
}

// Round 17
// 2139.113 us; speedup vs baseline: 1.1497x; 1.1497x over previous
//
#include <hip/hip_runtime.h>
#include <hip/hip_bf16.h>

// PeepholeLSTM: SEQ=512, BATCH=64, IN=512, HS=1024, FORGET_BIAS=0
// out = [hidden_seq (512*64*1024) | c_T (64*1024) | h_T (64*1024)] f32
//
// Round-17 = round-14 REVERT (proven best, 2140us) + spin-before-sleep gate backoff.
//   r14: pure-payload seqlock (publish exchanges -> vmcnt(0) -> per-(WG,wave) tag;
//   consumer: single poll of its 128 tags -> single-shot sc0sc1 loads, no retries).
//   r15 (plain/unique-slot consume) flat => not BW-bound. r16 (per-group gates)
//   regressed => detect must stay single (producers are synchronized; split gates
//   just serialize extra LLC RTs). Remaining 4.2us/step = structural cross-XCD
//   handoff latency x 512 serial steps: drain + tag flight + detect + payload RT
//   + compute. Alternatives blocked: batch-partition needs 8MB Wh/WG (>LDS);
//   single-XCD coherent needs 8MB in 4-5MB; relay/staging refuted (r10/12/13/16).

#define SEQN 512
#define BATCH 64
#define INDIM 512
#define HSZ 1024
#define NWG 128
#define DEPTH 4

typedef __attribute__((ext_vector_type(8))) short s16x8;
typedef __attribute__((ext_vector_type(4))) float f32x4;
typedef __attribute__((ext_vector_type(2))) float f32x2;
typedef __attribute__((ext_vector_type(4))) int i32x4;
typedef unsigned long long u64;

__device__ __forceinline__ short f2bf(float f) {
  __hip_bfloat16 b = __float2bfloat16(f);
  short s;
  __builtin_memcpy(&s, &b, 2);
  return s;
}
__device__ __forceinline__ float sigf(float x) { return 1.f / (1.f + __expf(-x)); }
__device__ __forceinline__ float tanh_fast(float x) { return 2.f / (1.f + __expf(-2.f * x)) - 1.f; }

// ---------------------------------------------------------------------------
// prep_w: col = gate*1024 + hidx; hidx = g*8+off; pc = off*4+gate.
__global__ __launch_bounds__(256) void prep_w(const float* __restrict__ W,
                                              short* __restrict__ WxP,
                                              short* __restrict__ WhP) {
  int idx = blockIdx.x * 256 + threadIdx.x;
  if (idx >= 1536 * 4096) return;
  int k = idx >> 12, col = idx & 4095;
  short b = f2bf(W[idx]);
  int gate = col >> 10, hidx = col & 1023;
  int g = hidx >> 3, off = hidx & 7;
  int pc = off * 4 + gate;
  if (k < 512) {
    WxP[(size_t)(((g * 64 + (k >> 3)) * 32 + pc) << 3) + (k & 7)] = b;
  } else {
    int kh = k - 512;
    WhP[(size_t)(((g * 128 + (kh >> 3)) * 32 + pc) << 3) + (kh & 7)] = b;
  }
}

// ---------------------------------------------------------------------------
// prep_x: x[t][m][k] f32 -> xbp[t][kb][m][8] bf16.
__global__ __launch_bounds__(256) void prep_x(const float* __restrict__ x,
                                              short* __restrict__ xbp) {
  int idx = blockIdx.x * 256 + threadIdx.x;
  if (idx >= SEQN * 64 * 64) return;
  int kb = idx & 63, m = (idx >> 6) & 63, t = idx >> 12;
  const float4* xp = reinterpret_cast<const float4*>(x + ((size_t)t * 64 + m) * 512 + kb * 8);
  float4 a = xp[0], c = xp[1];
  s16x8 v;
  v[0] = f2bf(a.x); v[1] = f2bf(a.y); v[2] = f2bf(a.z); v[3] = f2bf(a.w);
  v[4] = f2bf(c.x); v[5] = f2bf(c.y); v[6] = f2bf(c.z); v[7] = f2bf(c.w);
  reinterpret_cast<s16x8*>(xbp)[((size_t)t * 64 + kb) * 64 + m] = v;
}

// ---------------------------------------------------------------------------
// lstm_seq: 128 WGs x 256. WG g: hidden [8g,8g+8). Wave w: batch rows [16w,16w+16).
// Lane l: m = w*16+(l&15), q4 = l>>4, hidden cols c0 = 8g+q4, c1 = c0+4, all 4 gates.
// hq[t&3][gsrc 128][m 64][j 2] u64 = 4 bf16: j=0 -> cols 8gsrc+0..3, j=1 -> +4..7
//   (k-order: a dwordx4 [j0|j1] IS the MFMA B-frag for k-chunk gsrc).
// tagv[t&3][w 4][gsrc 128] u64 == t  <=>  producer (gsrc, wave w) h_{t-1} acked at LLC.
__global__ __launch_bounds__(256, 1) void lstm_seq(const short* __restrict__ xbp,
                                                   const short* __restrict__ WhP,
                                                   const short* __restrict__ WxP,
                                                   const float* __restrict__ bias,
                                                   const float* __restrict__ peep_i,
                                                   const float* __restrict__ peep_f,
                                                   const float* __restrict__ peep_o,
                                                   u64* hq,
                                                   u64* tagv,
                                                   float* __restrict__ out) {
  __shared__ short WhS[32768];   // 64KB [kb 128][pc 32][8]
  __shared__ short WxS[16384];   // 32KB [kb  64][pc 32][8]
  __shared__ float outS[512];    //  2KB
  int g = blockIdx.x;
  int tid = threadIdx.x, w = tid >> 6, l = tid & 63;
  {
    const s16x8* src = reinterpret_cast<const s16x8*>(WhP + (size_t)g * 32768);
    s16x8* dst = reinterpret_cast<s16x8*>(WhS);
#pragma unroll
    for (int i = 0; i < 16; ++i) dst[i * 256 + tid] = src[i * 256 + tid];
    const s16x8* src2 = reinterpret_cast<const s16x8*>(WxP + (size_t)g * 16384);
    s16x8* dst2 = reinterpret_cast<s16x8*>(WxS);
#pragma unroll
    for (int i = 0; i < 8; ++i) dst2[i * 256 + tid] = src2[i * 256 + tid];
  }
  int m = w * 16 + (l & 15), q4 = l >> 4, l15 = l & 15;
  int c0 = g * 8 + q4, c1 = c0 + 4;
  float bi0 = bias[c0], bj0 = bias[1024 + c0], bf0 = bias[2048 + c0], bo0 = bias[3072 + c0];
  float bi1 = bias[c1], bj1 = bias[1024 + c1], bf1 = bias[2048 + c1], bo1 = bias[3072 + c1];
  float pi0 = peep_i[c0], pf0 = peep_f[c0], po0 = peep_o[c0];
  float pi1 = peep_i[c1], pf1 = peep_f[c1], po1 = peep_o[c1];
  float cr0 = 0.f, cr1 = 0.f;
  s16x8* WhS16 = reinterpret_cast<s16x8*>(WhS);
  s16x8* WxS16 = reinterpret_cast<s16x8*>(WxS);
  __syncthreads();

// issue group G: 8 x dwordx4/lane (pure payload; each IS a B-frag), sc0 sc1 (LLC-fresh)
#define ISSUE(BANK, G)                                                                   \
  {                                                                                      \
    _Pragma("unroll") for (int i = 0; i < 8; ++i) {                                      \
      const u64* p_ = rdq + (size_t)((((G) * 8 + i) * 4 + q4) * 128 + m * 2);            \
      asm volatile("global_load_dwordx4 %0, %1, off sc0 sc1" : "=v"(BANK[i]) : "v"(p_)); \
    }                                                                                    \
  }
#define MFMAG(BANK, G)                                                                   \
  {                                                                                      \
    _Pragma("unroll") for (int i = 0; i < 8; ++i) {                                      \
      int kb_ = ((G) * 8 + i) * 4 + q4;                                                  \
      s16x8 bv;                                                                          \
      __builtin_memcpy(&bv, &BANK[i], 16);                                               \
      s16x8 a0 = WhS16[kb_ * 32 + l15];                                                  \
      s16x8 a1 = WhS16[kb_ * 32 + 16 + l15];                                             \
      acc0 = __builtin_amdgcn_mfma_f32_16x16x32_bf16(a0, bv, acc0, 0, 0, 0);             \
      acc1 = __builtin_amdgcn_mfma_f32_16x16x32_bf16(a1, bv, acc1, 0, 0, 0);             \
    }                                                                                    \
  }
#define VWAIT(N)                                                                         \
  asm volatile("s_waitcnt vmcnt(" #N ")" ::: "memory");                                  \
  __builtin_amdgcn_sched_barrier(0);

  for (int t = 0; t < SEQN; ++t) {
    f32x4 acc0 = {0.f, 0.f, 0.f, 0.f}, acc1 = {0.f, 0.f, 0.f, 0.f};
    // ---- x-projection (h-independent; overlaps other WGs' publish) ----
    {
      const s16x8* xt = reinterpret_cast<const s16x8*>(xbp) + (size_t)t * 4096;
#pragma unroll 4
      for (int kk = 0; kk < 16; ++kk) {
        int kb = kk * 4 + q4;
        s16x8 bx = xt[kb * 64 + m];
        s16x8 a0 = WxS16[kb * 32 + l15];
        s16x8 a1 = WxS16[kb * 32 + 16 + l15];
        acc0 = __builtin_amdgcn_mfma_f32_16x16x32_bf16(a0, bx, acc0, 0, 0, 0);
        acc1 = __builtin_amdgcn_mfma_f32_16x16x32_bf16(a1, bx, acc1, 0, 0, 0);
      }
    }
    if (t > 0) {
      // ---- GATE: this wave needs producer waves w (its rows) of all 128 WGs ----
      {
        const u64* gp = tagv + (size_t)(t & (DEPTH - 1)) * 512 + (size_t)w * 128 + 2 * l;
        int guard = 0;
        while (true) {
          i32x4 gv;
          asm volatile("global_load_dwordx4 %0, %1, off sc0 sc1" : "=v"(gv) : "v"(gp));
          asm volatile("s_waitcnt vmcnt(0)" ::: "memory");
          __builtin_amdgcn_sched_barrier(0);
          if (__all((int)((gv[0] == t) & (gv[2] == t)))) break;
          if (++guard > (1 << 13)) break;  // fail loud (wrong data), never hang
          if (guard > 2) __builtin_amdgcn_s_sleep(1);  // spin first, then backoff
        }
      }
      // ---- consume: single-shot loads, counted-vmcnt pipeline, no checks ----
      const u64* rdq = hq + (size_t)(t & (DEPTH - 1)) * 16384;
      i32x4 hA[8], hB[8];
      ISSUE(hA, 0);
      ISSUE(hB, 1);
      VWAIT(8);
      MFMAG(hA, 0);
      ISSUE(hA, 2);
      VWAIT(8);
      MFMAG(hB, 1);
      ISSUE(hB, 3);
      VWAIT(8);
      MFMAG(hA, 2);
      VWAIT(0);
      MFMAG(hB, 3);
    }
    // ---- elementwise (lane-local: all 4 gates of c0 and c1) ----
    float i0 = sigf(acc0[0] + bi0 + cr0 * pi0);
    float f0 = sigf(acc0[2] + bf0 + cr0 * pf0);
    float cn0 = f0 * cr0 + i0 * tanh_fast(acc0[1] + bj0);
    float o0 = sigf(acc0[3] + bo0 + cn0 * po0);
    float h0 = o0 * tanh_fast(cn0);
    cr0 = cn0;
    float i1 = sigf(acc1[0] + bi1 + cr1 * pi1);
    float f1 = sigf(acc1[2] + bf1 + cr1 * pf1);
    float cn1 = f1 * cr1 + i1 * tanh_fast(acc1[1] + bj1);
    float o1 = sigf(acc1[3] + bo1 + cn1 * po1);
    float h1 = o1 * tanh_fast(cn1);
    cr1 = cn1;
    // ---- publish: shfl-pack pure payload -> exchanges -> drain -> per-wave tag ----
    {
      unsigned myh = (unsigned)(unsigned short)f2bf(h0) |
                     ((unsigned)(unsigned short)f2bf(h1) << 16);
      int base = l15;
      unsigned va = (unsigned)__shfl((int)myh, base);
      unsigned vb = (unsigned)__shfl((int)myh, base + 16);
      unsigned vc = (unsigned)__shfl((int)myh, base + 32);
      unsigned vd = (unsigned)__shfl((int)myh, base + 48);
      if (q4 < 2) {
        u64 q;
        if (q4 == 0)  // j=0: h0 of lanes q4=0..3 = cols 8g+0..3 (k-order)
          q = (u64)(va & 0xFFFFu) | ((u64)(vb & 0xFFFFu) << 16) |
              ((u64)(vc & 0xFFFFu) << 32) | ((u64)(vd & 0xFFFFu) << 48);
        else          // j=1: h1 of lanes q4=0..3 = cols 8g+4..7
          q = (u64)(va >> 16) | ((u64)(vb >> 16) << 16) |
              ((u64)(vc >> 16) << 32) | ((u64)(vd >> 16) << 48);
        (void)__hip_atomic_exchange(
            hq + (size_t)((t + 1) & (DEPTH - 1)) * 16384 + g * 128 + m * 2 + q4, q,
            __ATOMIC_RELAXED, __HIP_MEMORY_SCOPE_AGENT);
      }
    }
    asm volatile("s_waitcnt vmcnt(0)" ::: "memory");  // payload acked at LLC
    if (l == 0)
      (void)__hip_atomic_exchange(
          tagv + (size_t)((t + 1) & (DEPTH - 1)) * 512 + (size_t)w * 128 + g,
          (u64)(unsigned)(t + 1), __ATOMIC_RELAXED, __HIP_MEMORY_SCOPE_AGENT);
    // ---- coalesced hidden_seq store via wave-local LDS stage (off critical path) ----
    outS[w * 128 + l15 * 8 + q4] = h0;
    outS[w * 128 + l15 * 8 + q4 + 4] = h1;
    {
      f32x2 v = *reinterpret_cast<f32x2*>(&outS[w * 128 + (l >> 2) * 8 + (l & 3) * 2]);
      int row = w * 16 + (l >> 2), col = g * 8 + (l & 3) * 2;
      __builtin_nontemporal_store(
          v, reinterpret_cast<f32x2*>(out + (size_t)t * 65536 + (size_t)row * 1024 + col));
    }
    if (t == SEQN - 1) {
      out[33554432ull + (size_t)m * 1024 + c0] = cn0;  // c_T
      out[33554432ull + (size_t)m * 1024 + c1] = cn1;
      out[33619968ull + (size_t)m * 1024 + c0] = h0;   // h_T
      out[33619968ull + (size_t)m * 1024 + c1] = h1;
    }
  }
#undef ISSUE
#undef MFMAG
#undef VWAIT
}

// ---------------------------------------------------------------------------
extern "C" void kernel_launch(void* const* d_in, const int* in_sizes, int n_in,
                              void* d_out, int out_size, void* d_ws, size_t ws_size,
                              hipStream_t stream) {
  const float* x      = (const float*)d_in[0];
  const float* W      = (const float*)d_in[1];
  const float* bias   = (const float*)d_in[2];
  const float* peep_i = (const float*)d_in[3];
  const float* peep_f = (const float*)d_in[4];
  const float* peep_o = (const float*)d_in[5];
  char* ws = (char*)d_ws;
  short* WxP = (short*)(ws);                   //  4194304 B
  short* WhP = (short*)(ws + 4194304ull);      //  8388608 B
  short* xbp = (short*)(ws + 12582912ull);     // 33554432 B
  u64* hq    = (u64*)(ws + 46137344ull);       //   524288 B (4 x 128KB pure-payload h)
  u64* tagv  = (u64*)(ws + 46661632ull);       //    16384 B (4 x 4KB per-wave tags)
  // zero tags every launch: stale tag values from a prior replay must never satisfy
  // this run's gate early (payload needs no memset: gate-pass implies this-run write)
  (void)hipMemsetAsync(tagv, 0, 16384ull, stream);
  prep_w<<<24576, 256, 0, stream>>>(W, WxP, WhP);
  prep_x<<<8192, 256, 0, stream>>>(x, xbp);
  lstm_seq<<<NWG, 256, 0, stream>>>(xbp, WhP, WxP, bias, peep_i, peep_f, peep_o, hq,
                                    tagv, (float*)d_out);
}